// Round 6
// baseline (165.366 us; speedup 1.0000x reference)
//
#include <hip/hip_runtime.h>

typedef __attribute__((ext_vector_type(8))) short bf16x8;
typedef __attribute__((ext_vector_type(4))) float floatx4;
typedef __attribute__((ext_vector_type(16))) float floatx16;
typedef __attribute__((ext_vector_type(4))) unsigned int uintx4;

#define B_    4
#define N_    2048
#define DIM_  512
#define NH_   8
#define HD_   64
#define SCALE_ 0.125f
#define SL2E_ (0.125f * 1.44269504f)   // scale * log2(e), folded into Q

// round-half-up bf16 convert: 2 VALU ops (vs 5 for RNE; differs only on exact
// ties, prob ~2^-24 on random data).
__device__ __forceinline__ unsigned short f32_to_bf16(float f) {
    return (unsigned short)((__float_as_uint(f) + 0x8000u) >> 16);
}

__device__ __forceinline__ float bf16_to_f32(unsigned short u) {
    return __uint_as_float(((unsigned int)u) << 16);
}

__device__ __forceinline__ floatx4 mfma16(bf16x8 a, bf16x8 b, floatx4 c) {
    return __builtin_amdgcn_mfma_f32_16x16x32_bf16(a, b, c, 0, 0, 0);
}

__device__ __forceinline__ floatx16 mfma32(bf16x8 a, bf16x8 b, floatx16 c) {
    return __builtin_amdgcn_mfma_f32_32x32x16_bf16(a, b, c, 0, 0, 0);
}

__device__ __forceinline__ floatx4 fzero4() {
    floatx4 z = {0.f, 0.f, 0.f, 0.f};
    return z;
}

__device__ __forceinline__ floatx16 fzero16() {
    floatx16 z;
#pragma unroll
    for (int i = 0; i < 16; i++) z[i] = 0.f;
    return z;
}

// packed f32x2 -> bf16x2 convert (RNE), 1 VALU op
__device__ __forceinline__ unsigned int cvt_pk_bf16(float lo, float hi) {
    unsigned int r;
    asm("v_cvt_pk_bf16_f32 %0, %1, %2" : "=v"(r) : "v"(lo), "v"(hi));
    return r;
}

// async global->LDS DMA, 16B per lane. lds dest is wave-uniform base; HW adds lane*16.
__device__ __forceinline__ void async16(const unsigned short* g, unsigned short* l) {
    __builtin_amdgcn_global_load_lds((const __attribute__((address_space(1))) void*)g,
                                     (__attribute__((address_space(3))) void*)l,
                                     16, 0, 0);
}

// ---------------- LayerNorm + weight-convert, single launch ----------------
__global__ __launch_bounds__(256) void ln_cvt_kernel(const float* __restrict__ x,
                                                     const float* __restrict__ w,
                                                     const float* __restrict__ b,
                                                     unsigned short* __restrict__ xn,
                                                     const float* __restrict__ srcA,
                                                     const float* __restrict__ srcB,
                                                     unsigned short* __restrict__ dstA,
                                                     unsigned short* __restrict__ dstB) {
    const int NWQ = 3 * DIM_ * DIM_;   // 786432
    if (blockIdx.x < 2048) {
        int wv = threadIdx.x >> 6;
        int lane = threadIdx.x & 63;
        int row = blockIdx.x * 4 + wv;
        const float4* xr = (const float4*)(x + (size_t)row * DIM_);
        float4 v0 = xr[lane * 2];
        float4 v1 = xr[lane * 2 + 1];
        float s  = (v0.x + v0.y + v0.z + v0.w) + (v1.x + v1.y + v1.z + v1.w);
        float sq = v0.x*v0.x + v0.y*v0.y + v0.z*v0.z + v0.w*v0.w +
                   v1.x*v1.x + v1.y*v1.y + v1.z*v1.z + v1.w*v1.w;
#pragma unroll
        for (int off = 1; off < 64; off <<= 1) {
            s  += __shfl_xor(s, off, 64);
            sq += __shfl_xor(sq, off, 64);
        }
        float mu   = s * (1.f / DIM_);
        float var  = sq * (1.f / DIM_) - mu * mu;
        float rstd = rsqrtf(var + 1e-5f);
        float4 w0 = ((const float4*)w)[lane * 2];
        float4 w1 = ((const float4*)w)[lane * 2 + 1];
        float4 b0 = ((const float4*)b)[lane * 2];
        float4 b1 = ((const float4*)b)[lane * 2 + 1];
        float y[8];
        y[0] = (v0.x - mu) * rstd * w0.x + b0.x;
        y[1] = (v0.y - mu) * rstd * w0.y + b0.y;
        y[2] = (v0.z - mu) * rstd * w0.z + b0.z;
        y[3] = (v0.w - mu) * rstd * w0.w + b0.w;
        y[4] = (v1.x - mu) * rstd * w1.x + b1.x;
        y[5] = (v1.y - mu) * rstd * w1.y + b1.y;
        y[6] = (v1.z - mu) * rstd * w1.z + b1.z;
        y[7] = (v1.w - mu) * rstd * w1.w + b1.w;
        uint4 pk;
        pk.x = (unsigned int)f32_to_bf16(y[0]) | ((unsigned int)f32_to_bf16(y[1]) << 16);
        pk.y = (unsigned int)f32_to_bf16(y[2]) | ((unsigned int)f32_to_bf16(y[3]) << 16);
        pk.z = (unsigned int)f32_to_bf16(y[4]) | ((unsigned int)f32_to_bf16(y[5]) << 16);
        pk.w = (unsigned int)f32_to_bf16(y[6]) | ((unsigned int)f32_to_bf16(y[7]) << 16);
        ((uint4*)(xn + (size_t)row * DIM_))[lane] = pk;
    } else {
        int e0 = ((blockIdx.x - 2048) * 256 + threadIdx.x) * 8;
        const float* src;
        unsigned short* dst;
        if (e0 < NWQ) { src = srcA + e0; dst = dstA + e0; }
        else          { src = srcB + (e0 - NWQ); dst = dstB + (e0 - NWQ); }
        float4 u0 = ((const float4*)src)[0];
        float4 u1 = ((const float4*)src)[1];
        uint4 pk;
        pk.x = (unsigned int)f32_to_bf16(u0.x) | ((unsigned int)f32_to_bf16(u0.y) << 16);
        pk.y = (unsigned int)f32_to_bf16(u0.z) | ((unsigned int)f32_to_bf16(u0.w) << 16);
        pk.z = (unsigned int)f32_to_bf16(u1.x) | ((unsigned int)f32_to_bf16(u1.y) << 16);
        pk.w = (unsigned int)f32_to_bf16(u1.z) | ((unsigned int)f32_to_bf16(u1.w) << 16);
        *(uint4*)dst = pk;
    }
}

// ======== m97-style LDS-staged GEMM core, 512-thread / 8-wave variant ========
#define GEMM_CORE512(A_, B_ptr, am0, bn0)                                           \
    __shared__ unsigned short Alds[2][128][32];                                     \
    __shared__ unsigned short Blds[2][128][32];                                     \
    int tid = threadIdx.x, lane = tid & 63, wid = tid >> 6;                         \
    int l15 = lane & 15, quad = lane >> 4;                                          \
    int wmloc = (wid >> 1) * 32, wnloc = (wid & 1) * 64;                            \
    int sr = lane >> 2;                                                             \
    int sc = (lane & 3) * 8;                                                        \
    int srow0 = 16 * wid;                                                           \
    floatx4 acc[2][4];                                                              \
    _Pragma("unroll")                                                               \
    for (int i = 0; i < 2; i++)                                                     \
        _Pragma("unroll")                                                           \
        for (int j = 0; j < 4; j++) acc[i][j] = fzero4();                           \
    int buf = 0;                                                                    \
    async16(A_ + (size_t)(am0 + srow0 + sr) * DIM_ + sc, &Alds[0][srow0][0]);       \
    async16(B_ptr + (size_t)(bn0 + srow0 + sr) * DIM_ + sc, &Blds[0][srow0][0]);    \
    __syncthreads();                                                                \
    for (int t = 0; t < 16; t++) {                                                  \
        if (t < 15) {                                                               \
            int k0 = (t + 1) * 32;                                                  \
            async16(A_ + (size_t)(am0 + srow0 + sr) * DIM_ + k0 + sc,               \
                    &Alds[buf ^ 1][srow0][0]);                                      \
            async16(B_ptr + (size_t)(bn0 + srow0 + sr) * DIM_ + k0 + sc,            \
                    &Blds[buf ^ 1][srow0][0]);                                      \
        }                                                                           \
        bf16x8 av[2], bv[4];                                                        \
        _Pragma("unroll")                                                           \
        for (int i = 0; i < 2; i++)                                                 \
            av[i] = *(const bf16x8*)(&Alds[buf][wmloc + 16 * i + l15][quad * 8]);   \
        _Pragma("unroll")                                                           \
        for (int j = 0; j < 4; j++)                                                 \
            bv[j] = *(const bf16x8*)(&Blds[buf][wnloc + 16 * j + l15][quad * 8]);   \
        _Pragma("unroll")                                                           \
        for (int i = 0; i < 2; i++)                                                 \
            _Pragma("unroll")                                                       \
            for (int j = 0; j < 4; j++)                                             \
                acc[i][j] = mfma16(av[i], bv[j], acc[i][j]);                        \
        __syncthreads();                                                            \
        buf ^= 1;                                                                   \
    }

// ---------------- QKV GEMM: [8192,512] x [1536,512]^T, scatter epilogue ----------------
__global__ __launch_bounds__(512, 6) void qkv_gemm(const unsigned short* __restrict__ A,
                                                   const unsigned short* __restrict__ Bw,
                                                   const float* __restrict__ bias,
                                                   unsigned short* __restrict__ Qh,
                                                   unsigned short* __restrict__ Kh,
                                                   unsigned short* __restrict__ Vt) {
    int am0 = blockIdx.x * 128, bn0 = blockIdx.y * 128;
    GEMM_CORE512(A, Bw, am0, bn0)

    if (bn0 >= 1024) {
        // ---- V path: per-wave LDS transpose -> coalesced Vt[d][t] b128 writes ----
        unsigned short* sc_ = &Alds[0][0][0] + wid * (16 * 40);   // 1280 B/wave
        int m0 = am0 + wmloc;
        int bidx = m0 >> 11;
        int t0 = m0 & 2047;
#pragma unroll
        for (int j = 0; j < 4; j++) {
            float bias_n = bias[bn0 + wnloc + 16 * j + l15];
#pragma unroll
            for (int i = 0; i < 2; i++)
#pragma unroll
                for (int r = 0; r < 4; r++)
                    sc_[l15 * 40 + 16 * i + quad * 4 + r] =
                        f32_to_bf16(acc[i][j][r] + bias_n);
            int nr = lane >> 2;                       // 0..15
            int rem = (bn0 - 1024) + wnloc + 16 * j + nr;
            int head = rem >> 6, d = rem & 63;
            bf16x8 vv = *(const bf16x8*)(sc_ + nr * 40 + (lane & 3) * 8);
            *(bf16x8*)(Vt + ((size_t)(bidx * NH_ + head) * HD_ + d) * N_ +
                       t0 + (lane & 3) * 8) = vv;
        }
    } else {
        // ---- Q/K path (32B-run b16 stores) ----
#pragma unroll
        for (int i = 0; i < 2; i++) {
#pragma unroll
            for (int j = 0; j < 4; j++) {
                int n = bn0 + wnloc + 16 * j + l15;
                float bias_n = bias[n];
                int which = n >> 9;
                int rem = n & 511;
                int head = rem >> 6;
                int d = rem & 63;
#pragma unroll
                for (int r = 0; r < 4; r++) {
                    int m = am0 + wmloc + 16 * i + quad * 4 + r;
                    int b = m >> 11;
                    int t = m & 2047;
                    float val = acc[i][j][r] + bias_n;
                    if (which == 0) {
                        Qh[((size_t)(b * NH_ + head) * N_ + t) * HD_ + d] =
                            f32_to_bf16(val * SL2E_);
                    } else {
                        Kh[((size_t)(b * NH_ + head) * N_ + t) * HD_ + d] =
                            f32_to_bf16(val);
                    }
                }
            }
        }
    }
}

// ---------------- Fused combine + out projection (unchanged) ----------------
__global__ __launch_bounds__(256, 4) void out_gemm_fused(const unsigned short* __restrict__ Opart,
                                                         const float* __restrict__ lpart,
                                                         const unsigned short* __restrict__ Bw,
                                                         const float* __restrict__ bias,
                                                         float* __restrict__ out) {
    __shared__ unsigned short Alds[2][64][36];    // padded, manual writes
    __shared__ unsigned short Blds[2][128][32];   // DMA-staged
    int tid = threadIdx.x, lane = tid & 63, wid = tid >> 6;
    int l15 = lane & 15, quad = lane >> 4;
    int wmloc = (wid >> 1) * 32, wnloc = (wid & 1) * 64;
    int am0 = blockIdx.x * 64, bn0 = blockIdx.y * 128;

    int arow = tid >> 2;
    int ac8 = (tid & 3) * 8;
    int token = am0 + arow;
    int bb = token >> 11;
    const size_t LSTR = (size_t)B_ * NH_ * N_;
    const size_t OSTR = (size_t)B_ * N_ * DIM_;
    const unsigned short* arow0 = Opart + (size_t)token * DIM_;
    const unsigned short* arow1 = arow0 + OSTR;

    int sr = lane >> 2;
    int sc = (lane & 3) * 8;

    floatx4 acc[2][4];
#pragma unroll
    for (int i = 0; i < 2; i++)
#pragma unroll
        for (int j = 0; j < 4; j++) acc[i][j] = fzero4();

#define STAGE_A(BUF, T)                                                         \
    {                                                                           \
        int k0 = (T) * 32;                                                      \
        int head = k0 >> 6;                                                     \
        size_t li = (size_t)(bb * NH_ + head) * N_ + (token & 2047);            \
        float l1 = lpart[li];                                                   \
        float l2 = lpart[LSTR + li];                                            \
        float inv = 1.f / (l1 + l2);                                            \
        float w1 = l1 * inv, w2 = l2 * inv;                                     \
        bf16x8 o0 = *(const bf16x8*)(arow0 + k0 + ac8);                         \
        bf16x8 o1 = *(const bf16x8*)(arow1 + k0 + ac8);                         \
        bf16x8 pk;                                                              \
        _Pragma("unroll")                                                       \
        for (int e = 0; e < 8; e++)                                             \
            pk[e] = (short)f32_to_bf16(                                         \
                w1 * bf16_to_f32((unsigned short)o0[e]) +                       \
                w2 * bf16_to_f32((unsigned short)o1[e]));                       \
        *(bf16x8*)(&Alds[BUF][arow][ac8]) = pk;                                 \
    }

#define STAGE_B(BUF, T)                                                         \
    {                                                                           \
        int k0 = (T) * 32;                                                      \
        _Pragma("unroll")                                                       \
        for (int i = 0; i < 2; i++) {                                           \
            int r0 = 32 * wid + 16 * i;                                         \
            async16(Bw + (size_t)(bn0 + r0 + sr) * DIM_ + k0 + sc,              \
                    &Blds[BUF][r0][0]);                                         \
        }                                                                       \
    }

    STAGE_B(0, 0)
    STAGE_A(0, 0)
    __syncthreads();
    int buf = 0;
    for (int t = 0; t < 16; t++) {
        if (t < 15) {
            STAGE_B(buf ^ 1, t + 1)
            STAGE_A(buf ^ 1, t + 1)
        }
        bf16x8 av[2], bv[4];
#pragma unroll
        for (int i = 0; i < 2; i++)
            av[i] = *(const bf16x8*)(&Alds[buf][wmloc + 16 * i + l15][quad * 8]);
#pragma unroll
        for (int j = 0; j < 4; j++)
            bv[j] = *(const bf16x8*)(&Blds[buf][wnloc + 16 * j + l15][quad * 8]);
#pragma unroll
        for (int i = 0; i < 2; i++)
#pragma unroll
            for (int j = 0; j < 4; j++)
                acc[i][j] = mfma16(av[i], bv[j], acc[i][j]);
        __syncthreads();
        buf ^= 1;
    }
#undef STAGE_A
#undef STAGE_B

#pragma unroll
    for (int i = 0; i < 2; i++) {
#pragma unroll
        for (int j = 0; j < 4; j++) {
            int n = bn0 + wnloc + 16 * j + l15;
            float bias_n = bias[n];
#pragma unroll
            for (int r = 0; r < 4; r++) {
                int m = am0 + wmloc + 16 * i + quad * 4 + r;
                out[(size_t)m * DIM_ + n] = acc[i][j][r] + bias_n;
            }
        }
    }
}

// ---------------- Flash attention v7: T15 cur/prev pipeline, 1 barrier/iter ----------------
// v6 post-mortem: counted-vmcnt null; waves are phase-locked (all QK, then all
// softmax, then all PV -> pipes ping-pong, 31%+37% busy, ~32% idle). v7:
// iteration i computes QK^T(i+1), then softmax(i+1) INTERLEAVED with PV(i)
// (independent streams: SM on VALU/trans, PV on MFMA). pa double-state, static
// indices (rule #20). One barrier/iter: stage of tile i+3 (slot (i-1)%4) is
// WAR-protected by this iter's barrier (last read of tile i-1 was PV(i-1),
// before the previous barrier). Steady-state vmcnt(2).
__global__ __launch_bounds__(512, 4) void attn_kernel(const unsigned short* __restrict__ Qh,
                                                      const unsigned short* __restrict__ Kh,
                                                      const unsigned short* __restrict__ Vtg,
                                                      unsigned short* __restrict__ Opart,
                                                      float* __restrict__ lpart) {
    int bh = blockIdx.y;
    int b = bh >> 3, head = bh & 7;
    int qt = blockIdx.x;
    int split = blockIdx.z;
    int kv0 = split << 10;                 // 0 or 1024
    int tid = threadIdx.x, lane = tid & 63, w = tid >> 6;   // w in [0,8)
    int l31 = lane & 31, hi = lane >> 5;
    int xr = l31 & 7;                      // read-side swizzle term (row & 7)

    const unsigned short* Qp = Qh + (size_t)bh * N_ * HD_;
    const unsigned short* Kg = Kh + (size_t)bh * N_ * HD_;
    const unsigned short* Vg = Vtg + (size_t)bh * HD_ * N_;

    int q0 = qt * 256 + w * 32;

    // Q as B-fragments: lane l31 = q row (output col), frag t covers d in [16t,16t+16)
    bf16x8 aQ[4];
    {
        const unsigned short* qrow = Qp + (size_t)(q0 + l31) * HD_ + hi * 8;
#pragma unroll
        for (int t = 0; t < 4; t++)
            aQ[t] = *(const bf16x8*)(qrow + 16 * t);
    }

    // [buf][K=0/V=1][row][64 shorts]; strides: buf 16384B, V 8192B, 32 rows 4096B
    __shared__ unsigned short KV[4][2][64][64];   // 64 KB ring
    __shared__ float l_sm[8][32];                 // wave-private 1/l broadcast

    int srow = lane >> 3;                 // 0..7
    int scol = ((lane & 7) ^ srow) * 8;   // pre-swizzled global source chunk

    // 4 per-lane swizzled base pointers; all reads = base + const offset
    const char* ptc[4];
#pragma unroll
    for (int t = 0; t < 4; t++)
        ptc[t] = (const char*)&KV[0][0][l31][(((2 * t + hi) ^ xr) * 8)];

    // wave w stages K rows [8w,8w+8) and V rows [8w,8w+8): 2 DMAs per tile
    const unsigned short* kSrc = Kg + (size_t)(kv0 + 8 * w + srow) * HD_ + scol;
    const unsigned short* vSrc = Vg + (size_t)(8 * w + srow) * N_ + kv0 + scol;

#define STAGE_KV(BUF, IT)                                                       \
    {                                                                           \
        async16(kSrc + (size_t)(IT) * 64 * HD_, &KV[BUF][0][8 * w][0]);         \
        async16(vSrc + (size_t)(IT) * 64, &KV[BUF][1][8 * w][0]);               \
    }

#define VMW(N)  asm volatile("s_waitcnt vmcnt(" #N ")" ::: "memory")
#define RBAR()  asm volatile("s_barrier" ::: "memory")

    floatx16 of[2];
    of[0] = fzero16();
    of[1] = fzero16();
    float lsA = 0.f, lsB = 0.f;   // per-lane partial row-sums (2 chains)
    bf16x8 pa[4];                 // P fragments of the PREVIOUS tile

// QK^T + softmax for one 32-k-slice (TAU) of tile in buffer QB -> panew[2TAU..2TAU+1]
#define QKSM_TAU(QB, TAU)                                                       \
    {                                                                           \
        bf16x8 kf0 = *(const bf16x8*)(ptc[0] + (QB) * 16384 + (TAU) * 4096);    \
        bf16x8 kf1 = *(const bf16x8*)(ptc[1] + (QB) * 16384 + (TAU) * 4096);    \
        bf16x8 kf2 = *(const bf16x8*)(ptc[2] + (QB) * 16384 + (TAU) * 4096);    \
        bf16x8 kf3 = *(const bf16x8*)(ptc[3] + (QB) * 16384 + (TAU) * 4096);    \
        floatx16 acc = fzero16();                                               \
        __builtin_amdgcn_s_setprio(1);                                          \
        acc = mfma32(kf0, aQ[0], acc);                                          \
        acc = mfma32(kf1, aQ[1], acc);                                          \
        acc = mfma32(kf2, aQ[2], acc);                                          \
        acc = mfma32(kf3, aQ[3], acc);                                          \
        __builtin_amdgcn_s_setprio(0);                                          \
        float p[16];                                                            \
        _Pragma("unroll")                                                       \
        for (int r = 0; r < 16; r += 2) {                                       \
            p[r]     = __builtin_amdgcn_exp2f(acc[r]);                          \
            p[r + 1] = __builtin_amdgcn_exp2f(acc[r + 1]);                      \
            lsA += p[r];                                                        \
            lsB += p[r + 1];                                                    \
        }                                                                       \
        unsigned int a0 = cvt_pk_bf16(p[0], p[1]);                              \
        unsigned int b0 = cvt_pk_bf16(p[4], p[5]);                              \
        unsigned int a1 = cvt_pk_bf16(p[2], p[3]);                              \
        unsigned int b1 = cvt_pk_bf16(p[6], p[7]);                              \
        unsigned int a2 = cvt_pk_bf16(p[8], p[9]);                              \
        unsigned int b2 = cvt_pk_bf16(p[12], p[13]);                            \
        unsigned int a3 = cvt_pk_bf16(p[10], p[11]);                            \
        unsigned int b3 = cvt_pk_bf16(p[14], p[15]);                            \
        asm("v_permlane32_swap_b32 %0, %1" : "+v"(a0), "+v"(b0));               \
        asm("v_permlane32_swap_b32 %0, %1" : "+v"(a1), "+v"(b1));               \
        asm("v_permlane32_swap_b32 %0, %1" : "+v"(a2), "+v"(b2));               \
        asm("v_permlane32_swap_b32 %0, %1" : "+v"(a3), "+v"(b3));               \
        uintx4 f0 = {a0, a1, b0, b1};                                           \
        uintx4 f1 = {a2, a3, b2, b3};                                           \
        panew[2 * (TAU)]     = __builtin_bit_cast(bf16x8, f0);                  \
        panew[2 * (TAU) + 1] = __builtin_bit_cast(bf16x8, f1);                  \
    }

// one PV k-slice S with the OLD pa on buffer PB
#define PVPAIR(PB, S)                                                           \
    {                                                                           \
        _Pragma("unroll")                                                       \
        for (int dt = 0; dt < 2; dt++) {                                        \
            bf16x8 vf = *(const bf16x8*)(ptc[S] + (PB) * 16384 + 8192 +         \
                                         dt * 4096);                            \
            of[dt] = mfma32(pa[S], vf, of[dt]);                                 \
        }                                                                       \
    }

// fused step: QK^T+softmax on tile in QB (next), PV on tile in PB (prev, old pa)
#define FUSED(QB, PB)                                                           \
    {                                                                           \
        bf16x8 panew[4];                                                        \
        QKSM_TAU(QB, 0)                                                         \
        __builtin_amdgcn_s_setprio(1);                                          \
        PVPAIR(PB, 0) PVPAIR(PB, 1)                                             \
        __builtin_amdgcn_s_setprio(0);                                          \
        QKSM_TAU(QB, 1)                                                         \
        __builtin_amdgcn_s_setprio(1);                                          \
        PVPAIR(PB, 2) PVPAIR(PB, 3)                                             \
        __builtin_amdgcn_s_setprio(0);                                          \
        pa[0] = panew[0]; pa[1] = panew[1];                                     \
        pa[2] = panew[2]; pa[3] = panew[3];                                     \
    }

// QK+softmax only (prologue, tile 0)
#define QKFIRST(QB)                                                             \
    {                                                                           \
        bf16x8 panew[4];                                                        \
        QKSM_TAU(QB, 0)                                                         \
        QKSM_TAU(QB, 1)                                                         \
        pa[0] = panew[0]; pa[1] = panew[1];                                     \
        pa[2] = panew[2]; pa[3] = panew[3];                                     \
    }

#define ITER(QB, PB, VN)                                                        \
    VMW(VN);                                                                    \
    RBAR();                                                                     \
    __builtin_amdgcn_sched_barrier(0);                                          \
    FUSED(QB, PB)

    // prologue: prefetch tiles 0..2, then QK+SM of tile 0
    STAGE_KV(0, 0)
    STAGE_KV(1, 1)
    STAGE_KV(2, 2)
    VMW(4);
    RBAR();
    __builtin_amdgcn_sched_barrier(0);
    QKFIRST(0)

    // i = 0..11 (stages tiles 3..14)
    for (int g = 0; g < 3; g++) {
        int t3 = g * 4 + 3;
        ITER(1, 0, 2); STAGE_KV(3, t3);
        ITER(2, 1, 2); STAGE_KV(0, t3 + 1);
        ITER(3, 2, 2); STAGE_KV(1, t3 + 2);
        ITER(0, 3, 2); STAGE_KV(2, t3 + 3);
    }
    // i = 12..14
    ITER(1, 0, 2); STAGE_KV(3, 15);
    ITER(2, 1, 2);
    ITER(3, 2, 0);
    // epilogue: PV of tile 15 (buf 3) with final pa; no barrier needed
    __builtin_amdgcn_s_setprio(1);
    PVPAIR(3, 0) PVPAIR(3, 1) PVPAIR(3, 2) PVPAIR(3, 3)
    __builtin_amdgcn_s_setprio(0);
#undef ITER
#undef QKFIRST
#undef FUSED
#undef PVPAIR
#undef QKSM_TAU
#undef STAGE_KV
#undef VMW
#undef RBAR

    // full row-sum for q=l31: this lane's 32 p's/iter + partner (hi^1) half
    float lsum = lsA + lsB;
    lsum += __shfl_xor(lsum, 32, 64);
    if (hi == 0) {
        l_sm[w][l31] = __builtin_amdgcn_rcpf(lsum);
        lpart[(size_t)split * B_ * NH_ * N_ + (size_t)bh * N_ + q0 + l31] = lsum;
    }
    // wave-private LDS: same-wave ds_write -> ds_read; force completion order
    asm volatile("s_waitcnt lgkmcnt(0)" ::: "memory");

    unsigned short* Od = Opart + (size_t)split * B_ * N_ * DIM_;
#pragma unroll
    for (int r = 0; r < 16; r++) {
        int qr = (r & 3) + 8 * (r >> 2) + 4 * hi;
        float inv = l_sm[w][qr];          // 2 distinct addrs per wave: broadcast
        int token = q0 + qr;
        size_t base = ((size_t)b * N_ + token) * DIM_ + (size_t)head * HD_;
#pragma unroll
        for (int dt = 0; dt < 2; dt++)
            Od[base + 32 * dt + l31] = f32_to_bf16(of[dt][r] * inv);
    }
}

extern "C" void kernel_launch(void* const* d_in, const int* in_sizes, int n_in,
                              void* d_out, int out_size, void* d_ws, size_t ws_size,
                              hipStream_t stream) {
    const float* x     = (const float*)d_in[0];
    const float* ln_w  = (const float*)d_in[1];
    const float* ln_b  = (const float*)d_in[2];
    const float* qkv_w = (const float*)d_in[3];
    const float* qkv_b = (const float*)d_in[4];
    const float* out_w = (const float*)d_in[5];
    const float* out_b = (const float*)d_in[6];
    float* out = (float*)d_out;

    char* ws = (char*)d_ws;
    const size_t TOK = (size_t)B_ * N_;                 // 8192
    unsigned short* xn    = (unsigned short*)ws;  ws += TOK * DIM_ * 2;
    unsigned short* wq_bf = (unsigned short*)ws;  ws += (size_t)3 * DIM_ * DIM_ * 2;
    unsigned short* wo_bf = (unsigned short*)ws;  ws += (size_t)DIM_ * DIM_ * 2;
    unsigned short* Qh    = (unsigned short*)ws;  ws += TOK * DIM_ * 2;
    unsigned short* Kh    = (unsigned short*)ws;  ws += TOK * DIM_ * 2;
    unsigned short* Vt    = (unsigned short*)ws;  ws += TOK * DIM_ * 2;
    unsigned short* Opart = (unsigned short*)ws;  ws += (size_t)2 * TOK * DIM_ * 2;
    float*          lpart = (float*)ws;           ws += (size_t)2 * B_ * NH_ * N_ * 4;

    // ln blocks: 2048; cvt blocks: (3*512*512 + 512*512)/(256*8) = 512
    ln_cvt_kernel<<<2048 + 512, 256, 0, stream>>>(x, ln_w, ln_b, xn,
                                                  qkv_w, out_w, wq_bf, wo_bf);
    qkv_gemm<<<dim3(TOK / 128, (3 * DIM_) / 128), 512, 0, stream>>>(xn, wq_bf, qkv_b, Qh, Kh, Vt);
    attn_kernel<<<dim3(N_ / 256, B_ * NH_, 2), 512, 0, stream>>>(Qh, Kh, Vt, Opart, lpart);
    out_gemm_fused<<<dim3(TOK / 64, DIM_ / 128), 256, 0, stream>>>(Opart, lpart, wo_bf, out_b, out);
}

// Round 7
// 152.217 us; speedup vs baseline: 1.0864x; 1.0864x over previous
//
#include <hip/hip_runtime.h>

typedef __attribute__((ext_vector_type(8))) short bf16x8;
typedef __attribute__((ext_vector_type(4))) float floatx4;
typedef __attribute__((ext_vector_type(16))) float floatx16;
typedef __attribute__((ext_vector_type(4))) unsigned int uintx4;

#define B_    4
#define N_    2048
#define DIM_  512
#define NH_   8
#define HD_   64
#define SCALE_ 0.125f
#define SL2E_ (0.125f * 1.44269504f)   // scale * log2(e), folded into Q

// round-half-up bf16 convert: 2 VALU ops (vs 5 for RNE; differs only on exact
// ties, prob ~2^-24 on random data).
__device__ __forceinline__ unsigned short f32_to_bf16(float f) {
    return (unsigned short)((__float_as_uint(f) + 0x8000u) >> 16);
}

__device__ __forceinline__ float bf16_to_f32(unsigned short u) {
    return __uint_as_float(((unsigned int)u) << 16);
}

__device__ __forceinline__ floatx4 mfma16(bf16x8 a, bf16x8 b, floatx4 c) {
    return __builtin_amdgcn_mfma_f32_16x16x32_bf16(a, b, c, 0, 0, 0);
}

__device__ __forceinline__ floatx16 mfma32(bf16x8 a, bf16x8 b, floatx16 c) {
    return __builtin_amdgcn_mfma_f32_32x32x16_bf16(a, b, c, 0, 0, 0);
}

__device__ __forceinline__ floatx4 fzero4() {
    floatx4 z = {0.f, 0.f, 0.f, 0.f};
    return z;
}

__device__ __forceinline__ floatx16 fzero16() {
    floatx16 z;
#pragma unroll
    for (int i = 0; i < 16; i++) z[i] = 0.f;
    return z;
}

// packed f32x2 -> bf16x2 convert (RNE), 1 VALU op
__device__ __forceinline__ unsigned int cvt_pk_bf16(float lo, float hi) {
    unsigned int r;
    asm("v_cvt_pk_bf16_f32 %0, %1, %2" : "=v"(r) : "v"(lo), "v"(hi));
    return r;
}

// async global->LDS DMA, 16B per lane. lds dest is wave-uniform base; HW adds lane*16.
__device__ __forceinline__ void async16(const unsigned short* g, unsigned short* l) {
    __builtin_amdgcn_global_load_lds((const __attribute__((address_space(1))) void*)g,
                                     (__attribute__((address_space(3))) void*)l,
                                     16, 0, 0);
}

// ---------------- LayerNorm + weight-convert, single launch ----------------
__global__ __launch_bounds__(256) void ln_cvt_kernel(const float* __restrict__ x,
                                                     const float* __restrict__ w,
                                                     const float* __restrict__ b,
                                                     unsigned short* __restrict__ xn,
                                                     const float* __restrict__ srcA,
                                                     const float* __restrict__ srcB,
                                                     unsigned short* __restrict__ dstA,
                                                     unsigned short* __restrict__ dstB) {
    const int NWQ = 3 * DIM_ * DIM_;   // 786432
    if (blockIdx.x < 2048) {
        int wv = threadIdx.x >> 6;
        int lane = threadIdx.x & 63;
        int row = blockIdx.x * 4 + wv;
        const float4* xr = (const float4*)(x + (size_t)row * DIM_);
        float4 v0 = xr[lane * 2];
        float4 v1 = xr[lane * 2 + 1];
        float s  = (v0.x + v0.y + v0.z + v0.w) + (v1.x + v1.y + v1.z + v1.w);
        float sq = v0.x*v0.x + v0.y*v0.y + v0.z*v0.z + v0.w*v0.w +
                   v1.x*v1.x + v1.y*v1.y + v1.z*v1.z + v1.w*v1.w;
#pragma unroll
        for (int off = 1; off < 64; off <<= 1) {
            s  += __shfl_xor(s, off, 64);
            sq += __shfl_xor(sq, off, 64);
        }
        float mu   = s * (1.f / DIM_);
        float var  = sq * (1.f / DIM_) - mu * mu;
        float rstd = rsqrtf(var + 1e-5f);
        float4 w0 = ((const float4*)w)[lane * 2];
        float4 w1 = ((const float4*)w)[lane * 2 + 1];
        float4 b0 = ((const float4*)b)[lane * 2];
        float4 b1 = ((const float4*)b)[lane * 2 + 1];
        float y[8];
        y[0] = (v0.x - mu) * rstd * w0.x + b0.x;
        y[1] = (v0.y - mu) * rstd * w0.y + b0.y;
        y[2] = (v0.z - mu) * rstd * w0.z + b0.z;
        y[3] = (v0.w - mu) * rstd * w0.w + b0.w;
        y[4] = (v1.x - mu) * rstd * w1.x + b1.x;
        y[5] = (v1.y - mu) * rstd * w1.y + b1.y;
        y[6] = (v1.z - mu) * rstd * w1.z + b1.z;
        y[7] = (v1.w - mu) * rstd * w1.w + b1.w;
        uint4 pk;
        pk.x = (unsigned int)f32_to_bf16(y[0]) | ((unsigned int)f32_to_bf16(y[1]) << 16);
        pk.y = (unsigned int)f32_to_bf16(y[2]) | ((unsigned int)f32_to_bf16(y[3]) << 16);
        pk.z = (unsigned int)f32_to_bf16(y[4]) | ((unsigned int)f32_to_bf16(y[5]) << 16);
        pk.w = (unsigned int)f32_to_bf16(y[6]) | ((unsigned int)f32_to_bf16(y[7]) << 16);
        ((uint4*)(xn + (size_t)row * DIM_))[lane] = pk;
    } else {
        int e0 = ((blockIdx.x - 2048) * 256 + threadIdx.x) * 8;
        const float* src;
        unsigned short* dst;
        if (e0 < NWQ) { src = srcA + e0; dst = dstA + e0; }
        else          { src = srcB + (e0 - NWQ); dst = dstB + (e0 - NWQ); }
        float4 u0 = ((const float4*)src)[0];
        float4 u1 = ((const float4*)src)[1];
        uint4 pk;
        pk.x = (unsigned int)f32_to_bf16(u0.x) | ((unsigned int)f32_to_bf16(u0.y) << 16);
        pk.y = (unsigned int)f32_to_bf16(u0.z) | ((unsigned int)f32_to_bf16(u0.w) << 16);
        pk.z = (unsigned int)f32_to_bf16(u1.x) | ((unsigned int)f32_to_bf16(u1.y) << 16);
        pk.w = (unsigned int)f32_to_bf16(u1.z) | ((unsigned int)f32_to_bf16(u1.w) << 16);
        *(uint4*)dst = pk;
    }
}

// ======== m97-style LDS-staged GEMM core, 512-thread / 8-wave variant ========
#define GEMM_CORE512(A_, B_ptr, am0, bn0)                                           \
    __shared__ unsigned short Alds[2][128][32];                                     \
    __shared__ unsigned short Blds[2][128][32];                                     \
    int tid = threadIdx.x, lane = tid & 63, wid = tid >> 6;                         \
    int l15 = lane & 15, quad = lane >> 4;                                          \
    int wmloc = (wid >> 1) * 32, wnloc = (wid & 1) * 64;                            \
    int sr = lane >> 2;                                                             \
    int sc = (lane & 3) * 8;                                                        \
    int srow0 = 16 * wid;                                                           \
    floatx4 acc[2][4];                                                              \
    _Pragma("unroll")                                                               \
    for (int i = 0; i < 2; i++)                                                     \
        _Pragma("unroll")                                                           \
        for (int j = 0; j < 4; j++) acc[i][j] = fzero4();                           \
    int buf = 0;                                                                    \
    async16(A_ + (size_t)(am0 + srow0 + sr) * DIM_ + sc, &Alds[0][srow0][0]);       \
    async16(B_ptr + (size_t)(bn0 + srow0 + sr) * DIM_ + sc, &Blds[0][srow0][0]);    \
    __syncthreads();                                                                \
    for (int t = 0; t < 16; t++) {                                                  \
        if (t < 15) {                                                               \
            int k0 = (t + 1) * 32;                                                  \
            async16(A_ + (size_t)(am0 + srow0 + sr) * DIM_ + k0 + sc,               \
                    &Alds[buf ^ 1][srow0][0]);                                      \
            async16(B_ptr + (size_t)(bn0 + srow0 + sr) * DIM_ + k0 + sc,            \
                    &Blds[buf ^ 1][srow0][0]);                                      \
        }                                                                           \
        bf16x8 av[2], bv[4];                                                        \
        _Pragma("unroll")                                                           \
        for (int i = 0; i < 2; i++)                                                 \
            av[i] = *(const bf16x8*)(&Alds[buf][wmloc + 16 * i + l15][quad * 8]);   \
        _Pragma("unroll")                                                           \
        for (int j = 0; j < 4; j++)                                                 \
            bv[j] = *(const bf16x8*)(&Blds[buf][wnloc + 16 * j + l15][quad * 8]);   \
        _Pragma("unroll")                                                           \
        for (int i = 0; i < 2; i++)                                                 \
            _Pragma("unroll")                                                       \
            for (int j = 0; j < 4; j++)                                             \
                acc[i][j] = mfma16(av[i], bv[j], acc[i][j]);                        \
        __syncthreads();                                                            \
        buf ^= 1;                                                                   \
    }

// ---------------- QKV GEMM: [8192,512] x [1536,512]^T, scatter epilogue ----------------
__global__ __launch_bounds__(512, 6) void qkv_gemm(const unsigned short* __restrict__ A,
                                                   const unsigned short* __restrict__ Bw,
                                                   const float* __restrict__ bias,
                                                   unsigned short* __restrict__ Qh,
                                                   unsigned short* __restrict__ Kh,
                                                   unsigned short* __restrict__ Vt) {
    int am0 = blockIdx.x * 128, bn0 = blockIdx.y * 128;
    GEMM_CORE512(A, Bw, am0, bn0)

    if (bn0 >= 1024) {
        // ---- V path: per-wave LDS transpose -> coalesced Vt[d][t] b128 writes ----
        unsigned short* sc_ = &Alds[0][0][0] + wid * (16 * 40);   // 1280 B/wave
        int m0 = am0 + wmloc;
        int bidx = m0 >> 11;
        int t0 = m0 & 2047;
#pragma unroll
        for (int j = 0; j < 4; j++) {
            float bias_n = bias[bn0 + wnloc + 16 * j + l15];
#pragma unroll
            for (int i = 0; i < 2; i++)
#pragma unroll
                for (int r = 0; r < 4; r++)
                    sc_[l15 * 40 + 16 * i + quad * 4 + r] =
                        f32_to_bf16(acc[i][j][r] + bias_n);
            int nr = lane >> 2;                       // 0..15
            int rem = (bn0 - 1024) + wnloc + 16 * j + nr;
            int head = rem >> 6, d = rem & 63;
            bf16x8 vv = *(const bf16x8*)(sc_ + nr * 40 + (lane & 3) * 8);
            *(bf16x8*)(Vt + ((size_t)(bidx * NH_ + head) * HD_ + d) * N_ +
                       t0 + (lane & 3) * 8) = vv;
        }
    } else {
        // ---- Q/K path: per-wave LDS bounce -> per-token coalesced b128 stores ----
        // wave's 64-n span = one head's full d range (n0 is 64-aligned).
        unsigned short* sc2 = &Alds[0][0][0] + wid * 1024;   // 2 KB/wave (16 tok x 64 d)
        int n0 = bn0 + wnloc;
        int which = n0 >> 9;
        int head = (n0 & 511) >> 6;
        unsigned short* dstBase = (which == 0) ? Qh : Kh;
        float mul = (which == 0) ? SL2E_ : 1.f;
#pragma unroll
        for (int i = 0; i < 2; i++) {
#pragma unroll
            for (int j = 0; j < 4; j++) {
                float bias_n = bias[n0 + 16 * j + l15];
#pragma unroll
                for (int r = 0; r < 4; r++)
                    sc2[(quad * 4 + r) * 64 + 16 * j + l15] =
                        f32_to_bf16((acc[i][j][r] + bias_n) * mul);
            }
            asm volatile("s_waitcnt lgkmcnt(0)" ::: "memory");
#pragma unroll
            for (int h = 0; h < 2; h++) {
                int tl = 8 * h + (lane >> 3);           // 0..15 local token
                int m = am0 + wmloc + 16 * i + tl;
                int bb2 = m >> 11, tt = m & 2047;
                bf16x8 row = *(const bf16x8*)(sc2 + tl * 64 + (lane & 7) * 8);
                *(bf16x8*)(dstBase + ((size_t)(bb2 * NH_ + head) * N_ + tt) * HD_ +
                           (lane & 7) * 8) = row;
            }
            // same-wave LDS ops are processed in order: next i's writes can't
            // pass this i's reads.
        }
    }
}

// ---------------- Fused combine + out projection (unchanged) ----------------
__global__ __launch_bounds__(256, 4) void out_gemm_fused(const unsigned short* __restrict__ Opart,
                                                         const float* __restrict__ lpart,
                                                         const unsigned short* __restrict__ Bw,
                                                         const float* __restrict__ bias,
                                                         float* __restrict__ out) {
    __shared__ unsigned short Alds[2][64][36];    // padded, manual writes
    __shared__ unsigned short Blds[2][128][32];   // DMA-staged
    int tid = threadIdx.x, lane = tid & 63, wid = tid >> 6;
    int l15 = lane & 15, quad = lane >> 4;
    int wmloc = (wid >> 1) * 32, wnloc = (wid & 1) * 64;
    int am0 = blockIdx.x * 64, bn0 = blockIdx.y * 128;

    int arow = tid >> 2;
    int ac8 = (tid & 3) * 8;
    int token = am0 + arow;
    int bb = token >> 11;
    const size_t LSTR = (size_t)B_ * NH_ * N_;
    const size_t OSTR = (size_t)B_ * N_ * DIM_;
    const unsigned short* arow0 = Opart + (size_t)token * DIM_;
    const unsigned short* arow1 = arow0 + OSTR;

    int sr = lane >> 2;
    int sc = (lane & 3) * 8;

    floatx4 acc[2][4];
#pragma unroll
    for (int i = 0; i < 2; i++)
#pragma unroll
        for (int j = 0; j < 4; j++) acc[i][j] = fzero4();

#define STAGE_A(BUF, T)                                                         \
    {                                                                           \
        int k0 = (T) * 32;                                                      \
        int head = k0 >> 6;                                                     \
        size_t li = (size_t)(bb * NH_ + head) * N_ + (token & 2047);            \
        float l1 = lpart[li];                                                   \
        float l2 = lpart[LSTR + li];                                            \
        float inv = 1.f / (l1 + l2);                                            \
        float w1 = l1 * inv, w2 = l2 * inv;                                     \
        bf16x8 o0 = *(const bf16x8*)(arow0 + k0 + ac8);                         \
        bf16x8 o1 = *(const bf16x8*)(arow1 + k0 + ac8);                         \
        bf16x8 pk;                                                              \
        _Pragma("unroll")                                                       \
        for (int e = 0; e < 8; e++)                                             \
            pk[e] = (short)f32_to_bf16(                                         \
                w1 * bf16_to_f32((unsigned short)o0[e]) +                       \
                w2 * bf16_to_f32((unsigned short)o1[e]));                       \
        *(bf16x8*)(&Alds[BUF][arow][ac8]) = pk;                                 \
    }

#define STAGE_B(BUF, T)                                                         \
    {                                                                           \
        int k0 = (T) * 32;                                                      \
        _Pragma("unroll")                                                       \
        for (int i = 0; i < 2; i++) {                                           \
            int r0 = 32 * wid + 16 * i;                                         \
            async16(Bw + (size_t)(bn0 + r0 + sr) * DIM_ + k0 + sc,              \
                    &Blds[BUF][r0][0]);                                         \
        }                                                                       \
    }

    STAGE_B(0, 0)
    STAGE_A(0, 0)
    __syncthreads();
    int buf = 0;
    for (int t = 0; t < 16; t++) {
        if (t < 15) {
            STAGE_B(buf ^ 1, t + 1)
            STAGE_A(buf ^ 1, t + 1)
        }
        bf16x8 av[2], bv[4];
#pragma unroll
        for (int i = 0; i < 2; i++)
            av[i] = *(const bf16x8*)(&Alds[buf][wmloc + 16 * i + l15][quad * 8]);
#pragma unroll
        for (int j = 0; j < 4; j++)
            bv[j] = *(const bf16x8*)(&Blds[buf][wnloc + 16 * j + l15][quad * 8]);
#pragma unroll
        for (int i = 0; i < 2; i++)
#pragma unroll
            for (int j = 0; j < 4; j++)
                acc[i][j] = mfma16(av[i], bv[j], acc[i][j]);
        __syncthreads();
        buf ^= 1;
    }
#undef STAGE_A
#undef STAGE_B

#pragma unroll
    for (int i = 0; i < 2; i++) {
#pragma unroll
        for (int j = 0; j < 4; j++) {
            int n = bn0 + wnloc + 16 * j + l15;
            float bias_n = bias[n];
#pragma unroll
            for (int r = 0; r < 4; r++) {
                int m = am0 + wmloc + 16 * i + quad * 4 + r;
                out[(size_t)m * DIM_ + n] = acc[i][j][r] + bias_n;
            }
        }
    }
}

// ---------------- Flash attention v8: 64 q-rows/wave, halved LDS volume ----------------
// v7 post-mortem: 5 schedule variants all ~46 us -> not schedule-bound. Pipe
// inventory per CU: LDS reads 27 us (dominant!) > VALU 16.6 > MFMA 13.8.
// v8 halves LDS volume: each wave owns 64 q rows (2 q-column-blocks); one
// kf/vf ds_read feeds BOTH q-blocks' MFMAs -> LDS bytes per unit work halve.
// VGPR ~200 -> launch_bounds(512,2), 2 waves/SIMD, 256 blocks. Persistent z16
// as first-mfma C kills per-iter acc zero-init movs. Simple v5 dbuf schedule.
__global__ __launch_bounds__(512, 2) void attn_kernel(const unsigned short* __restrict__ Qh,
                                                      const unsigned short* __restrict__ Kh,
                                                      const unsigned short* __restrict__ Vtg,
                                                      unsigned short* __restrict__ Opart,
                                                      float* __restrict__ lpart) {
    int bh = blockIdx.y;
    int b = bh >> 3, head = bh & 7;
    int qt = blockIdx.x;
    int split = blockIdx.z;
    int kv0 = split << 10;                 // 0 or 1024
    int tid = threadIdx.x, lane = tid & 63, w = tid >> 6;   // w in [0,8)
    int l31 = lane & 31, hi = lane >> 5;
    int xr = l31 & 7;                      // read-side swizzle term (row & 7)

    const unsigned short* Qp = Qh + (size_t)bh * N_ * HD_;
    const unsigned short* Kg = Kh + (size_t)bh * N_ * HD_;
    const unsigned short* Vg = Vtg + (size_t)bh * HD_ * N_;

    int q0 = qt * 512 + w * 64;

    // Q as B-fragments, 2 q-column-blocks: lane l31 = q row within block
    bf16x8 aQ[2][4];
#pragma unroll
    for (int qc = 0; qc < 2; qc++) {
        const unsigned short* qrow = Qp + (size_t)(q0 + 32 * qc + l31) * HD_ + hi * 8;
#pragma unroll
        for (int t = 0; t < 4; t++)
            aQ[qc][t] = *(const bf16x8*)(qrow + 16 * t);
    }

    // [buf][K=0/V=1][row][64 shorts]; strides: buf 16384B, V 8192B, 32 rows 4096B
    __shared__ unsigned short KV[2][2][64][64];   // 32 KB
    __shared__ float l_sm[8][64];                 // wave-private 1/l broadcast

    int srow = lane >> 3;                 // 0..7
    int scol = ((lane & 7) ^ srow) * 8;   // pre-swizzled global source chunk

    // 4 per-lane swizzled base pointers; all reads = base + const offset
    const char* ptc[4];
#pragma unroll
    for (int t = 0; t < 4; t++)
        ptc[t] = (const char*)&KV[0][0][l31][(((2 * t + hi) ^ xr) * 8)];

    // wave w stages K rows [8w,8w+8) and V rows [8w,8w+8): 2 DMAs per tile
    const unsigned short* kSrc = Kg + (size_t)(kv0 + 8 * w + srow) * HD_ + scol;
    const unsigned short* vSrc = Vg + (size_t)(8 * w + srow) * N_ + kv0 + scol;

#define STAGE_KV(BUF, IT)                                                       \
    {                                                                           \
        async16(kSrc + (size_t)(IT) * 64 * HD_, &KV[BUF][0][8 * w][0]);         \
        async16(vSrc + (size_t)(IT) * 64, &KV[BUF][1][8 * w][0]);               \
    }

    floatx16 of[2][2];
#pragma unroll
    for (int qc = 0; qc < 2; qc++)
#pragma unroll
        for (int dt = 0; dt < 2; dt++) of[qc][dt] = fzero16();
    float ls[2][2] = {{0.f, 0.f}, {0.f, 0.f}};
    const floatx16 z16 = fzero16();       // persistent zero C-operand

#define COMPUTE(BUF)                                                            \
    {                                                                           \
        bf16x8 pa[2][4];                                                        \
        _Pragma("unroll")                                                       \
        for (int tau = 0; tau < 2; tau++) {                                     \
            bf16x8 kf[4];                                                       \
            _Pragma("unroll")                                                   \
            for (int t = 0; t < 4; t++)                                         \
                kf[t] = *(const bf16x8*)(ptc[t] + (BUF) * 16384 + tau * 4096);  \
            _Pragma("unroll")                                                   \
            for (int qc = 0; qc < 2; qc++) {                                    \
                __builtin_amdgcn_s_setprio(1);                                  \
                floatx16 acc = mfma32(kf[0], aQ[qc][0], z16);                   \
                acc = mfma32(kf[1], aQ[qc][1], acc);                            \
                acc = mfma32(kf[2], aQ[qc][2], acc);                            \
                acc = mfma32(kf[3], aQ[qc][3], acc);                            \
                __builtin_amdgcn_s_setprio(0);                                  \
                float p[16];                                                    \
                _Pragma("unroll")                                               \
                for (int r = 0; r < 16; r += 2) {                               \
                    p[r]     = __builtin_amdgcn_exp2f(acc[r]);                  \
                    p[r + 1] = __builtin_amdgcn_exp2f(acc[r + 1]);              \
                    ls[qc][0] += p[r];                                          \
                    ls[qc][1] += p[r + 1];                                      \
                }                                                               \
                unsigned int a0 = cvt_pk_bf16(p[0], p[1]);                      \
                unsigned int b0 = cvt_pk_bf16(p[4], p[5]);                      \
                unsigned int a1 = cvt_pk_bf16(p[2], p[3]);                      \
                unsigned int b1 = cvt_pk_bf16(p[6], p[7]);                      \
                unsigned int a2 = cvt_pk_bf16(p[8], p[9]);                      \
                unsigned int b2 = cvt_pk_bf16(p[12], p[13]);                    \
                unsigned int a3 = cvt_pk_bf16(p[10], p[11]);                    \
                unsigned int b3 = cvt_pk_bf16(p[14], p[15]);                    \
                asm("v_permlane32_swap_b32 %0, %1" : "+v"(a0), "+v"(b0));       \
                asm("v_permlane32_swap_b32 %0, %1" : "+v"(a1), "+v"(b1));       \
                asm("v_permlane32_swap_b32 %0, %1" : "+v"(a2), "+v"(b2));       \
                asm("v_permlane32_swap_b32 %0, %1" : "+v"(a3), "+v"(b3));       \
                uintx4 f0 = {a0, a1, b0, b1};                                   \
                uintx4 f1 = {a2, a3, b2, b3};                                   \
                pa[qc][2 * tau]     = __builtin_bit_cast(bf16x8, f0);           \
                pa[qc][2 * tau + 1] = __builtin_bit_cast(bf16x8, f1);           \
            }                                                                   \
        }                                                                       \
        __builtin_amdgcn_s_setprio(1);                                          \
        _Pragma("unroll")                                                       \
        for (int s = 0; s < 4; s++) {                                           \
            _Pragma("unroll")                                                   \
            for (int dt = 0; dt < 2; dt++) {                                    \
                bf16x8 vf = *(const bf16x8*)(ptc[s] + (BUF) * 16384 + 8192 +    \
                                             dt * 4096);                        \
                of[0][dt] = mfma32(pa[0][s], vf, of[0][dt]);                    \
                of[1][dt] = mfma32(pa[1][s], vf, of[1][dt]);                    \
            }                                                                   \
        }                                                                       \
        __builtin_amdgcn_s_setprio(0);                                          \
    }

    STAGE_KV(0, 0)
    __syncthreads();

    for (int it2 = 0; it2 < 8; it2++) {
        int it = it2 * 2;
        STAGE_KV(1, it + 1)          // it+1 <= 15 always
        COMPUTE(0)
        __syncthreads();
        if (it2 < 7) STAGE_KV(0, it + 2)
        COMPUTE(1)
        __syncthreads();
    }
#undef STAGE_KV
#undef COMPUTE

    // full row-sums: this lane's halves + partner (hi^1) half, per q-block
#pragma unroll
    for (int qc = 0; qc < 2; qc++) {
        float lsum = ls[qc][0] + ls[qc][1];
        lsum += __shfl_xor(lsum, 32, 64);
        if (hi == 0) {
            l_sm[w][32 * qc + l31] = __builtin_amdgcn_rcpf(lsum);
            lpart[(size_t)split * B_ * NH_ * N_ + (size_t)bh * N_ +
                  q0 + 32 * qc + l31] = lsum;
        }
    }
    // wave-private LDS: same-wave ds_write -> ds_read; force completion order
    asm volatile("s_waitcnt lgkmcnt(0)" ::: "memory");

    unsigned short* Od = Opart + (size_t)split * B_ * N_ * DIM_;
#pragma unroll
    for (int r = 0; r < 16; r++) {
        int qr = (r & 3) + 8 * (r >> 2) + 4 * hi;
#pragma unroll
        for (int qc = 0; qc < 2; qc++) {
            float inv = l_sm[w][32 * qc + qr];
            int token = q0 + 32 * qc + qr;
            size_t base = ((size_t)b * N_ + token) * DIM_ + (size_t)head * HD_;
#pragma unroll
            for (int dt = 0; dt < 2; dt++)
                Od[base + 32 * dt + l31] = f32_to_bf16(of[qc][dt][r] * inv);
        }
    }
}

extern "C" void kernel_launch(void* const* d_in, const int* in_sizes, int n_in,
                              void* d_out, int out_size, void* d_ws, size_t ws_size,
                              hipStream_t stream) {
    const float* x     = (const float*)d_in[0];
    const float* ln_w  = (const float*)d_in[1];
    const float* ln_b  = (const float*)d_in[2];
    const float* qkv_w = (const float*)d_in[3];
    const float* qkv_b = (const float*)d_in[4];
    const float* out_w = (const float*)d_in[5];
    const float* out_b = (const float*)d_in[6];
    float* out = (float*)d_out;

    char* ws = (char*)d_ws;
    const size_t TOK = (size_t)B_ * N_;                 // 8192
    unsigned short* xn    = (unsigned short*)ws;  ws += TOK * DIM_ * 2;
    unsigned short* wq_bf = (unsigned short*)ws;  ws += (size_t)3 * DIM_ * DIM_ * 2;
    unsigned short* wo_bf = (unsigned short*)ws;  ws += (size_t)DIM_ * DIM_ * 2;
    unsigned short* Qh    = (unsigned short*)ws;  ws += TOK * DIM_ * 2;
    unsigned short* Kh    = (unsigned short*)ws;  ws += TOK * DIM_ * 2;
    unsigned short* Vt    = (unsigned short*)ws;  ws += TOK * DIM_ * 2;
    unsigned short* Opart = (unsigned short*)ws;  ws += (size_t)2 * TOK * DIM_ * 2;
    float*          lpart = (float*)ws;           ws += (size_t)2 * B_ * NH_ * N_ * 4;

    // ln blocks: 2048; cvt blocks: (3*512*512 + 512*512)/(256*8) = 512
    ln_cvt_kernel<<<2048 + 512, 256, 0, stream>>>(x, ln_w, ln_b, xn,
                                                  qkv_w, out_w, wq_bf, wo_bf);
    qkv_gemm<<<dim3(TOK / 128, (3 * DIM_) / 128), 512, 0, stream>>>(xn, wq_bf, qkv_b, Qh, Kh, Vt);
    attn_kernel<<<dim3(N_ / 512, B_ * NH_, 2), 512, 0, stream>>>(Qh, Kh, Vt, Opart, lpart);
    out_gemm_fused<<<dim3(TOK / 64, DIM_ / 128), 256, 0, stream>>>(Opart, lpart, wo_bf, out_b, out);
}